// Round 11
// baseline (507.810 us; speedup 1.0000x reference)
//
#include <hip/hip_runtime.h>

#define B_  2
#define S_  2048
#define D_  2048
#define H_  16
#define HD_ 128

typedef __bf16 bf16;
typedef __bf16 bf16x4 __attribute__((ext_vector_type(4)));
typedef __bf16 bf16x8 __attribute__((ext_vector_type(8)));
typedef float  f32x4  __attribute__((ext_vector_type(4)));
typedef unsigned int u32x4 __attribute__((ext_vector_type(4)));

// async global->LDS 16B copy: lds dst = wave-uniform base + lane*16
__device__ __forceinline__ void gld_lds16(const void* g, void* l) {
    __builtin_amdgcn_global_load_lds(
        (const __attribute__((address_space(1))) unsigned int*)g,
        (__attribute__((address_space(3))) unsigned int*)l, 16, 0, 0);
}

__device__ __forceinline__ f32x4 mfma16(bf16x8 a, bf16x8 b, f32x4 c) {
    return __builtin_amdgcn_mfma_f32_16x16x32_bf16(a, b, c, 0, 0, 0);
}

// raw barrier with compiler memory fence (does NOT drain vmcnt - that's the point)
#define BAR()  asm volatile("s_barrier" ::: "memory")

// ---------------- fused precast: x -> hi/lo planes, qm/km -> bf16 ----------------
__global__ __launch_bounds__(256)
void precast_all(const float* __restrict__ x, bf16* __restrict__ xh,
                 bf16* __restrict__ xl,
                 const float* __restrict__ qm, bf16* __restrict__ qmb,
                 const float* __restrict__ km, bf16* __restrict__ kmb,
                 const float* __restrict__ swp) {
    int bid = blockIdx.x;
    if (bid < 4096) {
        int i = (bid * 256 + threadIdx.x) * 8;
        float4 a = *(const float4*)(x + i);
        float4 b = *(const float4*)(x + i + 4);
        float av[8] = {a.x, a.y, a.z, a.w, b.x, b.y, b.z, b.w};
        bf16x8 h8, l8;
#pragma unroll
        for (int e = 0; e < 8; e++) {
            bf16 hv = (bf16)av[e];
            h8[e] = hv;
            l8[e] = (bf16)(av[e] - (float)hv);
        }
        *(bf16x8*)(xh + i) = h8;
        *(bf16x8*)(xl + i) = l8;
        return;
    }
    const float sw = swp[0];
    bid -= 4096;
    const float* src = qm; bf16* dst = qmb;
    if (bid >= 2048) { src = km; dst = kmb; bid -= 2048; }
    int i = (bid * 256 + threadIdx.x) * 8;
    float4 a = *(const float4*)(src + i);
    float4 b = *(const float4*)(src + i + 4);
    bf16x8 o;
    o[0] = (bf16)(a.x * sw); o[1] = (bf16)(a.y * sw);
    o[2] = (bf16)(a.z * sw); o[3] = (bf16)(a.w * sw);
    o[4] = (bf16)(b.x * sw); o[5] = (bf16)(b.y * sw);
    o[6] = (bf16)(b.z * sw); o[7] = (bf16)(b.w * sw);
    *(bf16x8*)(dst + i) = o;
}

// ---------------- precast masks: f32 * sw -> bf16 (single mask) ----------------
__global__ __launch_bounds__(256)
void precast_mask(const float* __restrict__ s0, bf16* __restrict__ d0,
                  const float* __restrict__ swp) {
    const float sw = swp[0];
    int i = (blockIdx.x * 256 + threadIdx.x) * 8;
    float4 a = *(const float4*)(s0 + i);
    float4 b = *(const float4*)(s0 + i + 4);
    bf16x8 o;
    o[0] = (bf16)(a.x * sw); o[1] = (bf16)(a.y * sw);
    o[2] = (bf16)(a.z * sw); o[3] = (bf16)(a.w * sw);
    o[4] = (bf16)(b.x * sw); o[5] = (bf16)(b.y * sw);
    o[6] = (bf16)(b.z * sw); o[7] = (bf16)(b.w * sw);
    *(bf16x8*)(d0 + i) = o;
}

// =================== 2-phase double-buffered GEMM (round-5 best) =======
// 4 waves, 2 blocks/CU, relaxed inner loop (compiler counted lgkm waits).
// MODE 0: q/k proj (virtual K=4096). MODE 1: v proj + V^T epilogue.
// MODE 2: out proj, f32 epilogue.
template<int BM, int BN, int MODE>
__global__ __launch_bounds__(256, 2)
void gemm2p(const bf16* __restrict__ Ah_g, const bf16* __restrict__ Al_g,
            const bf16* __restrict__ Bq, const bf16* __restrict__ Bk,
            const float* __restrict__ hm,
            bf16* __restrict__ o_qh, bf16* __restrict__ o_ql,
            bf16* __restrict__ o_kh, bf16* __restrict__ o_kl,
            bf16* __restrict__ o_vt, float* __restrict__ o_f32,
            int nt) {
    constexpr int IM = BM / 2 / 16;
    constexpr int JN = BN / 2 / 16;
    constexpr int IH = IM / 2;
    constexpr int ISSA = BM / 64;
    constexpr int ISSB = BN / 64;
    constexpr int BUFE = (BM + BN) * 32;
    constexpr int SMELEMS = (MODE == 1 && BN * (BM + 8) > 2 * BUFE)
                                ? BN * (BM + 8) : 2 * BUFE;
    __shared__ bf16 sm[SMELEMS];

    const int t = threadIdx.x;
    const int wave = t >> 6, lane = t & 63;
    const int lrow = lane & 15, quad = lane >> 4;
    const int wr = wave >> 1, wc = wave & 1;

    const int gx = gridDim.x;
    const int id0 = blockIdx.y * gx + blockIdx.x;
    const int nwg = gx * gridDim.y;
    const int id = (id0 & 7) * (nwg >> 3) + (id0 >> 3);
    const int m0 = (id / gx) * BM, n0 = (id % gx) * BN;

    const int nsec = (MODE == 0) ? (n0 & (D_ - 1)) : n0;
    const bf16* Bg = (MODE == 0 && n0 >= D_) ? Bk : Bq;

    const int arow = wr * (BM / 2) + lrow;
    const int brow = wc * (BN / 2) + lrow;
    const int gsw = (quad ^ ((lrow >> 1) & 3)) * 8;

    const int srr = lane >> 2, spg = lane & 3;
    const int ssw = (spg ^ ((srr >> 1) & 3)) * 8;

    auto stage_A = [&](int kt, int pbuf) {
        const bf16* As = (MODE == 0 && kt >= 64) ? Al_g : Ah_g;
        const int kc = ((MODE == 0) ? (kt & 63) : kt) * 32;
        bf16* buf = sm + pbuf * BUFE;
#pragma unroll
        for (int pp = 0; pp < ISSA; pp++) {
            int r0 = wave * (BM / 4) + pp * 16;
            gld_lds16(As + (size_t)(m0 + r0 + srr) * D_ + kc + ssw,
                      buf + r0 * 32);
        }
    };
    auto stage_B = [&](int kt, int pbuf) {
        const int kc = ((MODE == 0) ? (kt & 63) : kt) * 32;
        bf16* buf = sm + pbuf * BUFE + BM * 32;
#pragma unroll
        for (int pp = 0; pp < ISSB; pp++) {
            int r0 = wave * (BN / 4) + pp * 16;
            gld_lds16(Bg + (size_t)(nsec + r0 + srr) * D_ + kc + ssw,
                      buf + r0 * 32);
        }
    };

    f32x4 acc[IM][JN];
#pragma unroll
    for (int i = 0; i < IM; i++)
#pragma unroll
        for (int j = 0; j < JN; j++) acc[i][j] = (f32x4){0.f, 0.f, 0.f, 0.f};

    stage_A(0, 0); stage_B(0, 0); stage_B(1, 1);

    int p = 0;
    for (int kt = 0; kt < nt; ++kt) {
        if (kt < nt - 1) asm volatile("s_waitcnt vmcnt(2)" ::: "memory");
        else             asm volatile("s_waitcnt vmcnt(0)" ::: "memory");
        BAR();
        if (kt + 1 < nt) stage_A(kt + 1, p ^ 1);

        const bf16* Ab = sm + p * BUFE;
        const bf16* Bb = Ab + BM * 32;
        bf16x8 a[IH], b[JN];

#pragma unroll
        for (int j = 0; j < JN; j++)
            b[j] = *(const bf16x8*)&Bb[(brow + j * 16) * 32 + gsw];
#pragma unroll
        for (int i = 0; i < IH; i++)
            a[i] = *(const bf16x8*)&Ab[(arow + i * 16) * 32 + gsw];
        __builtin_amdgcn_s_setprio(1);
#pragma unroll
        for (int i = 0; i < IH; i++)
#pragma unroll
            for (int j = 0; j < JN; j++)
                acc[i][j] = mfma16(a[i], b[j], acc[i][j]);
        __builtin_amdgcn_s_setprio(0);
        BAR();

        if (kt + 2 < nt) stage_B(kt + 2, p);

#pragma unroll
        for (int i = 0; i < IH; i++)
            a[i] = *(const bf16x8*)&Ab[(arow + (IH + i) * 16) * 32 + gsw];
        __builtin_amdgcn_s_setprio(1);
#pragma unroll
        for (int i = 0; i < IH; i++)
#pragma unroll
            for (int j = 0; j < JN; j++)
                acc[IH + i][j] = mfma16(a[i], b[j], acc[IH + i][j]);
        __builtin_amdgcn_s_setprio(0);
        p ^= 1;
    }

    if constexpr (MODE == 0) {
        const bool isq = (n0 < D_);
        bf16* oh = isq ? o_qh : o_kh;
        bf16* ol = isq ? o_ql : o_kl;
#pragma unroll
        for (int j = 0; j < JN; j++) {
            int nb = nsec + wc * (BN / 2) + j * 16;
            int h = nb >> 7;
            float hv = hm[h];
#pragma unroll
            for (int i = 0; i < IM; i++) {
                int mB = m0 + wr * (BM / 2) + i * 16 + quad * 4;
                int bb = mB >> 11, s = mB & (S_ - 1);
                size_t idx0 = (((size_t)bb * H_ + h) * S_ + s) * HD_ + (nb & 127) + lrow;
#pragma unroll
                for (int r = 0; r < 4; r++) {
                    float v = acc[i][j][r] * hv;
                    bf16 hvv = (bf16)v;
                    bf16 lvv = (bf16)(v - (float)hvv);
                    oh[idx0 + (size_t)r * HD_] = hvv;
                    ol[idx0 + (size_t)r * HD_] = lvv;
                }
            }
        }
    }
    if constexpr (MODE == 1) {
        __syncthreads();
        bf16* tr = sm;
#pragma unroll
        for (int j = 0; j < JN; j++) {
            int nl = wc * (BN / 2) + j * 16 + lrow;
            float hv = hm[(n0 + nl) >> 7];
#pragma unroll
            for (int i = 0; i < IM; i++) {
                int ml = wr * (BM / 2) + i * 16 + quad * 4;
                bf16x4 pk;
#pragma unroll
                for (int r = 0; r < 4; r++) pk[r] = (bf16)(acc[i][j][r] * hv);
                *(bf16x4*)&tr[nl * 136 + ml] = pk;
            }
        }
        __syncthreads();
        const int bI = m0 >> 11;
        const int s0 = m0 & (S_ - 1);
#pragma unroll
        for (int w = 0; w < 8; w++) {
            int nrow = w * 16 + (t >> 4);
            int c = t & 15;
            bf16x8 vv = *(const bf16x8*)&tr[nrow * 136 + c * 8];
            int ng = n0 + nrow;
            int h = ng >> 7, hd = ng & 127;
            *(bf16x8*)&o_vt[((size_t)(bI * H_ + h) * HD_ + hd) * S_ + s0 + c * 8] = vv;
        }
    }
    if constexpr (MODE == 2) {
#pragma unroll
        for (int j = 0; j < JN; j++) {
            int n = n0 + wc * (BN / 2) + j * 16 + lrow;
#pragma unroll
            for (int i = 0; i < IM; i++) {
                int mB = m0 + wr * (BM / 2) + i * 16 + quad * 4;
#pragma unroll
                for (int r = 0; r < 4; r++)
                    o_f32[(size_t)(mB + r) * D_ + n] = acc[i][j][r];
            }
        }
    }
}

// ======== causal flash attention, QBLK=128, 8 waves (round-8 best config) ======
// T14 reg-prefetch staging, __launch_bounds__(512,2). NEW vs round 8: balanced
// CU pairing. tiles(qb)=2qb+2 ranges 2..32; old mapping paired qb with qb-8 on
// a CU (sums 20..48, kernel ends at the 48-tile CU). New: ids 0..255 -> qb
// 15..8 (longest-first preserved), ids 256..511 -> qb 0..7 so id and id+256
// (same CU under round-robin dispatch) sum to exactly 15 -> 34 tiles per CU.
// If blocks instead run as two sequential rounds, behavior == round 8.
#define SPLD 72

__global__ __launch_bounds__(512, 2)
void attn_kernel(const bf16* __restrict__ qh_, const bf16* __restrict__ ql_,
                 const bf16* __restrict__ kh_, const bf16* __restrict__ kl_,
                 const bf16* __restrict__ vt_, const float* __restrict__ am,
                 bf16* __restrict__ outp) {
    const int id = blockIdx.x;
    const int half = id >> 8;                     // 0: ids 0..255, 1: 256..511
    const int id2 = id & 255;
    const int xcd = id2 & 7, slot = id2 >> 3;     // slot 0..31
    const int bh = xcd * 4 + (slot & 3);          // 4 bh per XCD (L2 locality)
    const int qb = half ? (slot >> 2)             // 0..7
                        : (15 - (slot >> 2));     // 15..8, longest first
    const int b = bh >> 4, h = bh & 15;
    const int i0 = qb * 128;
    const int t = threadIdx.x, wave = t >> 6, lane = t & 63;
    const int lrow = lane & 15, quad = lane >> 4;

    __shared__ bf16 skh[64 * 128];                // swizzled [j][d]
    __shared__ bf16 skl[64 * 128];
    __shared__ bf16 svt[128 * 64];                // swizzled [d][j]
    __shared__ bf16 sp[8][16 * SPLD];             // per-wave P strip
    __shared__ float samadd[S_];                  // (1-am)*-1e4 table

    const size_t kbase = (size_t)bh * S_ * HD_;
    const size_t vbase = (size_t)bh * HD_ * S_;

    // stage amadd table once (512 thr x 4 f32)
    {
        int j = t * 4;
        float4 a0 = *(const float4*)(am + b * S_ + j);
        float4 r0 = {(1.0f - a0.x) * -10000.0f, (1.0f - a0.y) * -10000.0f,
                     (1.0f - a0.z) * -10000.0f, (1.0f - a0.w) * -10000.0f};
        *(float4*)&samadd[j] = r0;
    }

    // Q fragments (hi+lo) straight to registers — per-wave 16 rows
    const int qrow = i0 + wave * 16 + lrow;
    bf16x8 qhf[4], qlf[4];
#pragma unroll
    for (int c = 0; c < 4; c++) {
        qhf[c] = *(const bf16x8*)&qh_[kbase + (size_t)qrow * HD_ + c * 32 + quad * 8];
        qlf[c] = *(const bf16x8*)&ql_[kbase + (size_t)qrow * HD_ + c * 32 + quad * 8];
    }

    // prefetch registers (24 VGPRs): K hi 2, K lo 2, V 2 (split over 8 waves)
    u32x4 kpre[4], vpre[2];
    auto issueKV = [&](int j0) {
#pragma unroll
        for (int p = 0; p < 2; p++) {
            int rb = wave * 8 + p * 4;
            int r = rb + (lane >> 4);
            int gl = ((lane & 15) ^ (r & 7)) * 8;
            kpre[p]     = *(const u32x4*)(kh_ + kbase + (size_t)(j0 + r) * HD_ + gl);
            kpre[2 + p] = *(const u32x4*)(kl_ + kbase + (size_t)(j0 + r) * HD_ + gl);
        }
#pragma unroll
        for (int p = 0; p < 2; p++) {
            int db = wave * 16 + p * 8;
            int d = db + (lane >> 3);
            int gl = ((lane & 7) ^ (d & 7)) * 8;
            vpre[p] = *(const u32x4*)(vt_ + vbase + (size_t)d * S_ + j0 + gl);
        }
    };
    auto writeKV = [&]() {
#pragma unroll
        for (int p = 0; p < 2; p++) {
            int rb = wave * 8 + p * 4;
            *(u32x4*)&skh[rb * 128 + lane * 8] = kpre[p];
            *(u32x4*)&skl[rb * 128 + lane * 8] = kpre[2 + p];
        }
#pragma unroll
        for (int p = 0; p < 2; p++) {
            int db = wave * 16 + p * 8;
            *(u32x4*)&svt[db * 64 + lane * 8] = vpre[p];
        }
    };

    float m_i[4], l_i[4];
    f32x4 O[8];
#pragma unroll
    for (int r = 0; r < 4; r++) { m_i[r] = -INFINITY; l_i[r] = 0.f; }
#pragma unroll
    for (int n2 = 0; n2 < 8; n2++) O[n2] = (f32x4){0.f, 0.f, 0.f, 0.f};

    const float scale = 0.08838834764831845f;  // 1/sqrt(128)
    const int wbase = i0 + wave * 16;          // this wave's first q-row
    const int jmax = i0 + 64;                  // last tile start

    issueKV(0);                                // prologue prefetch
    __syncthreads();                           // samadd visible

    for (int j0 = 0; j0 <= jmax; j0 += 64) {
        BAR();                                 // all waves done reading prev LDS
        writeKV();                             // reg deps -> compiler counted vmcnt
        if (j0 + 64 <= jmax) issueKV(j0 + 64); // regs free after ds_write issue
        asm volatile("s_waitcnt lgkmcnt(0)" ::: "memory"); // my ds_writes done
        BAR();                                 // LDS tile visible to all

        // wave-uniform skip: tile entirely above causal diagonal for this wave
        if (j0 > wbase + 15) continue;

        float amadd[4];
#pragma unroll
        for (int nt = 0; nt < 4; nt++)
            amadd[nt] = samadd[j0 + nt * 16 + lrow];

        // QK^T: 16 rows x 64 cols, split 3-MFMA, swizzled B-frag reads
        f32x4 s4[4];
#pragma unroll
        for (int nt = 0; nt < 4; nt++) s4[nt] = (f32x4){0.f, 0.f, 0.f, 0.f};
        __builtin_amdgcn_s_setprio(1);
#pragma unroll
        for (int c = 0; c < 4; c++) {
#pragma unroll
            for (int nt = 0; nt < 4; nt++) {
                int ka = (nt * 16 + lrow) * 128 + (((c * 4 + quad) ^ (lrow & 7)) * 8);
                bf16x8 kb8 = *(const bf16x8*)&skh[ka];
                bf16x8 lb8 = *(const bf16x8*)&skl[ka];
                s4[nt] = mfma16(qhf[c], kb8, s4[nt]);
                s4[nt] = mfma16(qhf[c], lb8, s4[nt]);
                s4[nt] = mfma16(qlf[c], kb8, s4[nt]);
            }
        }
        __builtin_amdgcn_s_setprio(0);

        const bool needmask = (j0 + 63 > wbase);
#pragma unroll
        for (int r = 0; r < 4; r++) {
            const int rglob = wbase + quad * 4 + r;
            float sv[4], pw[4];
            float mx = -INFINITY;
#pragma unroll
            for (int nt = 0; nt < 4; nt++) {
                float xv = s4[nt][r] * scale + amadd[nt];
                if (needmask && (j0 + nt * 16 + lrow) > rglob) xv = -INFINITY;
                sv[nt] = xv;
                mx = fmaxf(mx, xv);
            }
#pragma unroll
            for (int off = 1; off < 16; off <<= 1) mx = fmaxf(mx, __shfl_xor(mx, off));
            float mnew = fmaxf(m_i[r], mx);
            float alpha = __expf(m_i[r] - mnew);
            float ps = 0.f;
#pragma unroll
            for (int nt = 0; nt < 4; nt++) { pw[nt] = __expf(sv[nt] - mnew); ps += pw[nt]; }
#pragma unroll
            for (int off = 1; off < 16; off <<= 1) ps += __shfl_xor(ps, off);
            l_i[r] = l_i[r] * alpha + ps;
            m_i[r] = mnew;
#pragma unroll
            for (int n2 = 0; n2 < 8; n2++) O[n2][r] *= alpha;
#pragma unroll
            for (int nt = 0; nt < 4; nt++)
                sp[wave][(quad * 4 + r) * SPLD + nt * 16 + lrow] = (bf16)pw[nt];
        }
        asm volatile("s_waitcnt lgkmcnt(0)" ::: "memory");   // sp per-wave

        // PV: O += P * V, swizzled V^T frag reads
        __builtin_amdgcn_s_setprio(1);
#pragma unroll
        for (int k2 = 0; k2 < 2; k2++) {
            bf16x8 pf = *(const bf16x8*)&sp[wave][lrow * SPLD + k2 * 32 + quad * 8];
            const int gp = ((quad + k2 * 4) ^ (lrow & 7)) * 8;
#pragma unroll
            for (int n2 = 0; n2 < 8; n2++) {
                bf16x8 vf8 = *(const bf16x8*)&svt[(n2 * 16 + lrow) * 64 + gp];
                O[n2] = mfma16(pf, vf8, O[n2]);
            }
        }
        __builtin_amdgcn_s_setprio(0);
    }

    float inv[4];
#pragma unroll
    for (int r = 0; r < 4; r++) inv[r] = 1.0f / l_i[r];
#pragma unroll
    for (int n2 = 0; n2 < 8; n2++)
#pragma unroll
        for (int r = 0; r < 4; r++) {
            int srow = i0 + wave * 16 + quad * 4 + r;
            outp[((size_t)(b * S_ + srow)) * D_ + h * HD_ + n2 * 16 + lrow] =
                (bf16)(O[n2][r] * inv[r]);
        }
}

// =================== launch ===================
extern "C" void kernel_launch(void* const* d_in, const int* in_sizes, int n_in,
                              void* d_out, int out_size, void* d_ws, size_t ws_size,
                              hipStream_t stream) {
    const float* x  = (const float*)d_in[0];
    const float* qm = (const float*)d_in[1];
    const float* km = (const float*)d_in[2];
    const float* vm = (const float*)d_in[3];
    const float* om = (const float*)d_in[4];
    const float* hm = (const float*)d_in[5];
    const float* am = (const float*)d_in[6];
    const float* sw = (const float*)d_in[7];
    float* out = (float*)d_out;

    const size_t P = (size_t)B_ * H_ * S_ * HD_ * sizeof(bf16);   // 16 MiB
    char* ws = (char*)d_ws;
    bf16* xh = (bf16*)(ws + 0 * P);
    bf16* xl = (bf16*)(ws + 1 * P);
    bf16* qh = (bf16*)(ws + 2 * P);
    bf16* ql = (bf16*)(ws + 3 * P);
    bf16* kh = (bf16*)(ws + 4 * P);
    bf16* kl = (bf16*)(ws + 5 * P);
    bf16* attn_out = xh;
    bf16* vmb = xl;
    bf16* omb = qh;
    bf16* vt  = (bf16*)d_out;
    bf16* qmb = (bf16*)((char*)d_out + 16u * 1024 * 1024);
    bf16* kmb = (bf16*)((char*)d_out + 24u * 1024 * 1024);

    precast_all<<<8192, 256, 0, stream>>>(x, xh, xl, qm, qmb, km, kmb, sw);

    // q/k projection: 256x128 tiles, virtual K=4096 (hi|lo), 512 blocks = 2/CU
    gemm2p<256, 128, 0><<<dim3(32, 16), 256, 0, stream>>>(
        xh, xl, qmb, kmb, hm, qh, ql, kh, kl, nullptr, nullptr, 128);

    // v projection (hi only): 128x128 tiles, 512 blocks; writes V^T directly
    precast_mask<<<2048, 256, 0, stream>>>(vm, vmb, sw);
    gemm2p<128, 128, 1><<<dim3(16, 32), 256, 0, stream>>>(
        xh, nullptr, vmb, nullptr, hm,
        nullptr, nullptr, nullptr, nullptr, vt, nullptr, 64);

    // attention: 512 blocks, QBLK=128, 8 waves, balanced CU pairing
    attn_kernel<<<512, 512, 0, stream>>>(qh, ql, kh, kl, vt, am, attn_out);

    // output projection: 128x128 tiles, 512 blocks, f32 out
    precast_mask<<<2048, 256, 0, stream>>>(om, omb, sw);
    gemm2p<128, 128, 2><<<dim3(16, 32), 256, 0, stream>>>(
        attn_out, nullptr, omb, nullptr, hm,
        nullptr, nullptr, nullptr, nullptr, nullptr, out, 64);
}

// Round 12
// 463.581 us; speedup vs baseline: 1.0954x; 1.0954x over previous
//
#include <hip/hip_runtime.h>

#define B_  2
#define S_  2048
#define D_  2048
#define H_  16
#define HD_ 128

typedef __bf16 bf16;
typedef __bf16 bf16x4 __attribute__((ext_vector_type(4)));
typedef __bf16 bf16x8 __attribute__((ext_vector_type(8)));
typedef float  f32x4  __attribute__((ext_vector_type(4)));
typedef unsigned int u32x4 __attribute__((ext_vector_type(4)));

// async global->LDS 16B copy: lds dst = wave-uniform base + lane*16
__device__ __forceinline__ void gld_lds16(const void* g, void* l) {
    __builtin_amdgcn_global_load_lds(
        (const __attribute__((address_space(1))) unsigned int*)g,
        (__attribute__((address_space(3))) unsigned int*)l, 16, 0, 0);
}

__device__ __forceinline__ f32x4 mfma16(bf16x8 a, bf16x8 b, f32x4 c) {
    return __builtin_amdgcn_mfma_f32_16x16x32_bf16(a, b, c, 0, 0, 0);
}

// raw barrier with compiler memory fence (does NOT drain vmcnt - that's the point)
#define BAR()  asm volatile("s_barrier" ::: "memory")

// ---------------- fused precast: x -> hi/lo planes, qm/km -> bf16 ----------------
__global__ __launch_bounds__(256)
void precast_all(const float* __restrict__ x, bf16* __restrict__ xh,
                 bf16* __restrict__ xl,
                 const float* __restrict__ qm, bf16* __restrict__ qmb,
                 const float* __restrict__ km, bf16* __restrict__ kmb,
                 const float* __restrict__ swp) {
    int bid = blockIdx.x;
    if (bid < 4096) {
        int i = (bid * 256 + threadIdx.x) * 8;
        float4 a = *(const float4*)(x + i);
        float4 b = *(const float4*)(x + i + 4);
        float av[8] = {a.x, a.y, a.z, a.w, b.x, b.y, b.z, b.w};
        bf16x8 h8, l8;
#pragma unroll
        for (int e = 0; e < 8; e++) {
            bf16 hv = (bf16)av[e];
            h8[e] = hv;
            l8[e] = (bf16)(av[e] - (float)hv);
        }
        *(bf16x8*)(xh + i) = h8;
        *(bf16x8*)(xl + i) = l8;
        return;
    }
    const float sw = swp[0];
    bid -= 4096;
    const float* src = qm; bf16* dst = qmb;
    if (bid >= 2048) { src = km; dst = kmb; bid -= 2048; }
    int i = (bid * 256 + threadIdx.x) * 8;
    float4 a = *(const float4*)(src + i);
    float4 b = *(const float4*)(src + i + 4);
    bf16x8 o;
    o[0] = (bf16)(a.x * sw); o[1] = (bf16)(a.y * sw);
    o[2] = (bf16)(a.z * sw); o[3] = (bf16)(a.w * sw);
    o[4] = (bf16)(b.x * sw); o[5] = (bf16)(b.y * sw);
    o[6] = (bf16)(b.z * sw); o[7] = (bf16)(b.w * sw);
    *(bf16x8*)(dst + i) = o;
}

// ---------------- precast masks: f32 * sw -> bf16 (single mask) ----------------
__global__ __launch_bounds__(256)
void precast_mask(const float* __restrict__ s0, bf16* __restrict__ d0,
                  const float* __restrict__ swp) {
    const float sw = swp[0];
    int i = (blockIdx.x * 256 + threadIdx.x) * 8;
    float4 a = *(const float4*)(s0 + i);
    float4 b = *(const float4*)(s0 + i + 4);
    bf16x8 o;
    o[0] = (bf16)(a.x * sw); o[1] = (bf16)(a.y * sw);
    o[2] = (bf16)(a.z * sw); o[3] = (bf16)(a.w * sw);
    o[4] = (bf16)(b.x * sw); o[5] = (bf16)(b.y * sw);
    o[6] = (bf16)(b.z * sw); o[7] = (bf16)(b.w * sw);
    *(bf16x8*)(d0 + i) = o;
}

// =================== 2-phase double-buffered GEMM (q/k projection) =======
// round-5 best structure: 4 waves, 2 blocks/CU, relaxed inner loop.
// Virtual K=4096 (xh kt<64, xl kt>=64); hi/lo split scatter epilogue.
__global__ __launch_bounds__(256, 2)
void gemm2p(const bf16* __restrict__ Ah_g, const bf16* __restrict__ Al_g,
            const bf16* __restrict__ Bq, const bf16* __restrict__ Bk,
            const float* __restrict__ hm,
            bf16* __restrict__ o_qh, bf16* __restrict__ o_ql,
            bf16* __restrict__ o_kh, bf16* __restrict__ o_kl,
            int nt) {
    constexpr int BM = 256, BN = 128;
    constexpr int IM = 8, JN = 4, IH = 4;
    constexpr int ISSA = 4, ISSB = 2;
    constexpr int BUFE = (BM + BN) * 32;
    __shared__ bf16 sm[2 * BUFE];

    const int t = threadIdx.x;
    const int wave = t >> 6, lane = t & 63;
    const int lrow = lane & 15, quad = lane >> 4;
    const int wr = wave >> 1, wc = wave & 1;

    const int gx = gridDim.x;
    const int id0 = blockIdx.y * gx + blockIdx.x;
    const int nwg = gx * gridDim.y;
    const int id = (id0 & 7) * (nwg >> 3) + (id0 >> 3);
    const int m0 = (id / gx) * BM, n0 = (id % gx) * BN;

    const int nsec = n0 & (D_ - 1);
    const bf16* Bg = (n0 >= D_) ? Bk : Bq;

    const int arow = wr * (BM / 2) + lrow;
    const int brow = wc * (BN / 2) + lrow;
    const int gsw = (quad ^ ((lrow >> 1) & 3)) * 8;

    const int srr = lane >> 2, spg = lane & 3;
    const int ssw = (spg ^ ((srr >> 1) & 3)) * 8;

    auto stage_A = [&](int kt, int pbuf) {
        const bf16* As = (kt >= 64) ? Al_g : Ah_g;
        const int kc = (kt & 63) * 32;
        bf16* buf = sm + pbuf * BUFE;
#pragma unroll
        for (int pp = 0; pp < ISSA; pp++) {
            int r0 = wave * (BM / 4) + pp * 16;
            gld_lds16(As + (size_t)(m0 + r0 + srr) * D_ + kc + ssw,
                      buf + r0 * 32);
        }
    };
    auto stage_B = [&](int kt, int pbuf) {
        const int kc = (kt & 63) * 32;
        bf16* buf = sm + pbuf * BUFE + BM * 32;
#pragma unroll
        for (int pp = 0; pp < ISSB; pp++) {
            int r0 = wave * (BN / 4) + pp * 16;
            gld_lds16(Bg + (size_t)(nsec + r0 + srr) * D_ + kc + ssw,
                      buf + r0 * 32);
        }
    };

    f32x4 acc[IM][JN];
#pragma unroll
    for (int i = 0; i < IM; i++)
#pragma unroll
        for (int j = 0; j < JN; j++) acc[i][j] = (f32x4){0.f, 0.f, 0.f, 0.f};

    stage_A(0, 0); stage_B(0, 0); stage_B(1, 1);

    int p = 0;
    for (int kt = 0; kt < nt; ++kt) {
        if (kt < nt - 1) asm volatile("s_waitcnt vmcnt(2)" ::: "memory");
        else             asm volatile("s_waitcnt vmcnt(0)" ::: "memory");
        BAR();
        if (kt + 1 < nt) stage_A(kt + 1, p ^ 1);

        const bf16* Ab = sm + p * BUFE;
        const bf16* Bb = Ab + BM * 32;
        bf16x8 a[IH], b[JN];

#pragma unroll
        for (int j = 0; j < JN; j++)
            b[j] = *(const bf16x8*)&Bb[(brow + j * 16) * 32 + gsw];
#pragma unroll
        for (int i = 0; i < IH; i++)
            a[i] = *(const bf16x8*)&Ab[(arow + i * 16) * 32 + gsw];
        __builtin_amdgcn_s_setprio(1);
#pragma unroll
        for (int i = 0; i < IH; i++)
#pragma unroll
            for (int j = 0; j < JN; j++)
                acc[i][j] = mfma16(a[i], b[j], acc[i][j]);
        __builtin_amdgcn_s_setprio(0);
        BAR();

        if (kt + 2 < nt) stage_B(kt + 2, p);

#pragma unroll
        for (int i = 0; i < IH; i++)
            a[i] = *(const bf16x8*)&Ab[(arow + (IH + i) * 16) * 32 + gsw];
        __builtin_amdgcn_s_setprio(1);
#pragma unroll
        for (int i = 0; i < IH; i++)
#pragma unroll
            for (int j = 0; j < JN; j++)
                acc[IH + i][j] = mfma16(a[i], b[j], acc[IH + i][j]);
        __builtin_amdgcn_s_setprio(0);
        p ^= 1;
    }

    const bool isq = (n0 < D_);
    bf16* oh = isq ? o_qh : o_kh;
    bf16* ol = isq ? o_ql : o_kl;
#pragma unroll
    for (int j = 0; j < JN; j++) {
        int nb = nsec + wc * (BN / 2) + j * 16;
        int h = nb >> 7;
        float hv = hm[h];
#pragma unroll
        for (int i = 0; i < IM; i++) {
            int mB = m0 + wr * (BM / 2) + i * 16 + quad * 4;
            int bb = mB >> 11, s = mB & (S_ - 1);
            size_t idx0 = (((size_t)bb * H_ + h) * S_ + s) * HD_ + (nb & 127) + lrow;
#pragma unroll
            for (int r = 0; r < 4; r++) {
                float v = acc[i][j][r] * hv;
                bf16 hvv = (bf16)v;
                bf16 lvv = (bf16)(v - (float)hvv);
                oh[idx0 + (size_t)r * HD_] = hvv;
                ol[idx0 + (size_t)r * HD_] = lvv;
            }
        }
    }
}

// =========== 128x128 BK=64 GEMM for v / out projections (NEW) ===========
// Same relaxed 2-phase schedule, but BK=64: per K-tile 16 ds_reads -> 32 MFMA,
// barriers per MFMA halved vs BK=32 (v/out measured at ~400 TF, half qk's
// efficiency; overhead amortization is the lever). 128B LDS rows, swizzle
// slot = group ^ (row&7) (stage source pre-swizzled; quarter-wave = 2-way,
// free). 512 blocks, 2/CU (LDS 64KB*2=128 <= 160). Accumulation order is
// bit-identical to old BK=32 kt-pairs. MODE 1: v + V^T epilogue. MODE 2: f32.
template<int MODE>
__global__ __launch_bounds__(256, 2)
void gemm64(const bf16* __restrict__ A_g, const bf16* __restrict__ B_g,
            const float* __restrict__ hm,
            bf16* __restrict__ o_vt, float* __restrict__ o_f32, int nt) {
    constexpr int BM = 128, BN = 128;
    constexpr int IM = 4, JN = 4, IH = 2;
    constexpr int BUFE = (BM + BN) * 64;       // 16384 elem = 32 KiB / buffer
    __shared__ bf16 sm[2 * BUFE];              // 64 KiB (MODE1 tr fits inside)

    const int t = threadIdx.x;
    const int wave = t >> 6, lane = t & 63;
    const int lrow = lane & 15, quad = lane >> 4;
    const int wr = wave >> 1, wc = wave & 1;

    const int gx = gridDim.x;
    const int id0 = blockIdx.y * gx + blockIdx.x;
    const int nwg = gx * gridDim.y;
    const int id = (id0 & 7) * (nwg >> 3) + (id0 >> 3);
    const int m0 = (id / gx) * BM, n0 = (id % gx) * BN;

    const int arow = wr * 64 + lrow;
    const int brow = wc * 64 + lrow;
    const int g0e = (quad ^ (lrow & 7)) * 8;          // kk=0 slot
    const int g1e = ((quad + 4) ^ (lrow & 7)) * 8;    // kk=1 slot

    // staging: 8 rows x 8 groups per 1KB issue; source col pre-swizzled
    const int srr8 = lane >> 3, sgp = lane & 7;
    const int ssw = (sgp ^ srr8) * 8;                 // (row&7)==srr8 per issue

    auto stage_A = [&](int kt, int pbuf) {
        const int kc = kt * 64;
        bf16* buf = sm + pbuf * BUFE;
#pragma unroll
        for (int pp = 0; pp < 4; pp++) {
            int r0 = wave * 32 + pp * 8;
            gld_lds16(A_g + (size_t)(m0 + r0 + srr8) * D_ + kc + ssw,
                      buf + r0 * 64);
        }
    };
    auto stage_B = [&](int kt, int pbuf) {
        const int kc = kt * 64;
        bf16* buf = sm + pbuf * BUFE + BM * 64;
#pragma unroll
        for (int pp = 0; pp < 4; pp++) {
            int r0 = wave * 32 + pp * 8;
            gld_lds16(B_g + (size_t)(n0 + r0 + srr8) * D_ + kc + ssw,
                      buf + r0 * 64);
        }
    };

    f32x4 acc[IM][JN];
#pragma unroll
    for (int i = 0; i < IM; i++)
#pragma unroll
        for (int j = 0; j < JN; j++) acc[i][j] = (f32x4){0.f, 0.f, 0.f, 0.f};

    stage_A(0, 0); stage_B(0, 0); stage_B(1, 1);

    int p = 0;
    for (int kt = 0; kt < nt; ++kt) {
        // FIFO/wave: [A(kt) x4, B(kt+1) x4] -> vmcnt(4) completes A(kt)+older
        if (kt < nt - 1) asm volatile("s_waitcnt vmcnt(4)" ::: "memory");
        else             asm volatile("s_waitcnt vmcnt(0)" ::: "memory");
        BAR();
        if (kt + 1 < nt) stage_A(kt + 1, p ^ 1);

        const bf16* Ab = sm + p * BUFE;
        const bf16* Bb = Ab + BM * 64;
        bf16x8 b0[JN], b1[JN], a0[IH], a1[IH];

        // phase A: read ALL B (both k-halves) + A-upper; MFMA upper 16
#pragma unroll
        for (int j = 0; j < JN; j++) {
            b0[j] = *(const bf16x8*)&Bb[(brow + j * 16) * 64 + g0e];
            b1[j] = *(const bf16x8*)&Bb[(brow + j * 16) * 64 + g1e];
        }
#pragma unroll
        for (int i = 0; i < IH; i++) {
            a0[i] = *(const bf16x8*)&Ab[(arow + i * 16) * 64 + g0e];
            a1[i] = *(const bf16x8*)&Ab[(arow + i * 16) * 64 + g1e];
        }
        __builtin_amdgcn_s_setprio(1);
#pragma unroll
        for (int i = 0; i < IH; i++)
#pragma unroll
            for (int j = 0; j < JN; j++) {
                acc[i][j] = mfma16(a0[i], b0[j], acc[i][j]);
                acc[i][j] = mfma16(a1[i], b1[j], acc[i][j]);
            }
        __builtin_amdgcn_s_setprio(0);
        BAR();                  // all waves' B reads consumed by MFMAs above

        if (kt + 2 < nt) stage_B(kt + 2, p);

        // phase B: A-lower; MFMA lower 16
#pragma unroll
        for (int i = 0; i < IH; i++) {
            a0[i] = *(const bf16x8*)&Ab[(arow + (IH + i) * 16) * 64 + g0e];
            a1[i] = *(const bf16x8*)&Ab[(arow + (IH + i) * 16) * 64 + g1e];
        }
        __builtin_amdgcn_s_setprio(1);
#pragma unroll
        for (int i = 0; i < IH; i++)
#pragma unroll
            for (int j = 0; j < JN; j++) {
                acc[IH + i][j] = mfma16(a0[i], b0[j], acc[IH + i][j]);
                acc[IH + i][j] = mfma16(a1[i], b1[j], acc[IH + i][j]);
            }
        __builtin_amdgcn_s_setprio(0);
        p ^= 1;
    }

    if constexpr (MODE == 1) {
        // LDS transpose in dead staging buffers, then coalesced V^T write
        __syncthreads();
        bf16* tr = sm;                          // [BN=128][136]
#pragma unroll
        for (int j = 0; j < JN; j++) {
            int nl = wc * 64 + j * 16 + lrow;
            float hv = hm[(n0 + nl) >> 7];
#pragma unroll
            for (int i = 0; i < IM; i++) {
                int ml = wr * 64 + i * 16 + quad * 4;
                bf16x4 pk;
#pragma unroll
                for (int r = 0; r < 4; r++) pk[r] = (bf16)(acc[i][j][r] * hv);
                *(bf16x4*)&tr[nl * 136 + ml] = pk;
            }
        }
        __syncthreads();
        const int bI = m0 >> 11;
        const int s0 = m0 & (S_ - 1);
#pragma unroll
        for (int w = 0; w < 8; w++) {
            int nrow = w * 16 + (t >> 4);
            int c = t & 15;
            bf16x8 vv = *(const bf16x8*)&tr[nrow * 136 + c * 8];
            int ng = n0 + nrow;
            int h = ng >> 7, hd = ng & 127;
            *(bf16x8*)&o_vt[((size_t)(bI * H_ + h) * HD_ + hd) * S_ + s0 + c * 8] = vv;
        }
    }
    if constexpr (MODE == 2) {
#pragma unroll
        for (int j = 0; j < JN; j++) {
            int n = n0 + wc * 64 + j * 16 + lrow;
#pragma unroll
            for (int i = 0; i < IM; i++) {
                int mB = m0 + wr * 64 + i * 16 + quad * 4;
#pragma unroll
                for (int r = 0; r < 4; r++)
                    o_f32[(size_t)(mB + r) * D_ + n] = acc[i][j][r];
            }
        }
    }
}

// ======== causal flash attention (EXACT round-8 best: 474.7 composite) ========
// QBLK=128, 8 waves, T14 reg-prefetch, launch_bounds(512,2), mapping
// qb = 15-(slot>>2) over all 512 ids (r11's balanced pairing regressed -33us).
#define SPLD 72

__global__ __launch_bounds__(512, 2)
void attn_kernel(const bf16* __restrict__ qh_, const bf16* __restrict__ ql_,
                 const bf16* __restrict__ kh_, const bf16* __restrict__ kl_,
                 const bf16* __restrict__ vt_, const float* __restrict__ am,
                 bf16* __restrict__ outp) {
    // 512 blocks: id = slot*8 + xcd; 4 bh per XCD; biggest q-blocks first
    const int id = blockIdx.x;
    const int xcd = id & 7, slot = id >> 3;       // slot 0..63
    const int bh = xcd * 4 + (slot & 3);
    const int qb = 15 - (slot >> 2);              // 16 q-blocks of 128 rows
    const int b = bh >> 4, h = bh & 15;
    const int i0 = qb * 128;
    const int t = threadIdx.x, wave = t >> 6, lane = t & 63;
    const int lrow = lane & 15, quad = lane >> 4;

    __shared__ bf16 skh[64 * 128];                // swizzled [j][d]
    __shared__ bf16 skl[64 * 128];
    __shared__ bf16 svt[128 * 64];                // swizzled [d][j]
    __shared__ bf16 sp[8][16 * SPLD];             // per-wave P strip
    __shared__ float samadd[S_];                  // (1-am)*-1e4 table

    const size_t kbase = (size_t)bh * S_ * HD_;
    const size_t vbase = (size_t)bh * HD_ * S_;

    // stage amadd table once (512 thr x 4 f32)
    {
        int j = t * 4;
        float4 a0 = *(const float4*)(am + b * S_ + j);
        float4 r0 = {(1.0f - a0.x) * -10000.0f, (1.0f - a0.y) * -10000.0f,
                     (1.0f - a0.z) * -10000.0f, (1.0f - a0.w) * -10000.0f};
        *(float4*)&samadd[j] = r0;
    }

    // Q fragments (hi+lo) straight to registers — per-wave 16 rows
    const int qrow = i0 + wave * 16 + lrow;
    bf16x8 qhf[4], qlf[4];
#pragma unroll
    for (int c = 0; c < 4; c++) {
        qhf[c] = *(const bf16x8*)&qh_[kbase + (size_t)qrow * HD_ + c * 32 + quad * 8];
        qlf[c] = *(const bf16x8*)&ql_[kbase + (size_t)qrow * HD_ + c * 32 + quad * 8];
    }

    // prefetch registers (24 VGPRs): K hi 2, K lo 2, V 2 (split over 8 waves)
    u32x4 kpre[4], vpre[2];
    auto issueKV = [&](int j0) {
#pragma unroll
        for (int p = 0; p < 2; p++) {
            int rb = wave * 8 + p * 4;
            int r = rb + (lane >> 4);
            int gl = ((lane & 15) ^ (r & 7)) * 8;
            kpre[p]     = *(const u32x4*)(kh_ + kbase + (size_t)(j0 + r) * HD_ + gl);
            kpre[2 + p] = *(const u32x4*)(kl_ + kbase + (size_t)(j0 + r) * HD_ + gl);
        }
#pragma unroll
        for (int p = 0; p < 2; p++) {
            int db = wave * 16 + p * 8;
            int d = db + (lane >> 3);
            int gl = ((lane & 7) ^ (d & 7)) * 8;
            vpre[p] = *(const u32x4*)(vt_ + vbase + (size_t)d * S_ + j0 + gl);
        }
    };
    auto writeKV = [&]() {
#pragma unroll
        for (int p = 0; p < 2; p++) {
            int rb = wave * 8 + p * 4;
            *(u32x4*)&skh[rb * 128 + lane * 8] = kpre[p];
            *(u32x4*)&skl[rb * 128 + lane * 8] = kpre[2 + p];
        }
#pragma unroll
        for (int p = 0; p < 2; p++) {
            int db = wave * 16 + p * 8;
            *(u32x4*)&svt[db * 64 + lane * 8] = vpre[p];
        }
    };

    float m_i[4], l_i[4];
    f32x4 O[8];
#pragma unroll
    for (int r = 0; r < 4; r++) { m_i[r] = -INFINITY; l_i[r] = 0.f; }
#pragma unroll
    for (int n2 = 0; n2 < 8; n2++) O[n2] = (f32x4){0.f, 0.f, 0.f, 0.f};

    const float scale = 0.08838834764831845f;  // 1/sqrt(128)
    const int wbase = i0 + wave * 16;          // this wave's first q-row
    const int jmax = i0 + 64;                  // last tile start

    issueKV(0);                                // prologue prefetch
    __syncthreads();                           // samadd visible

    for (int j0 = 0; j0 <= jmax; j0 += 64) {
        BAR();                                 // all waves done reading prev LDS
        writeKV();                             // reg deps -> compiler counted vmcnt
        if (j0 + 64 <= jmax) issueKV(j0 + 64); // regs free after ds_write issue
        asm volatile("s_waitcnt lgkmcnt(0)" ::: "memory"); // my ds_writes done
        BAR();                                 // LDS tile visible to all

        // wave-uniform skip: tile entirely above causal diagonal for this wave
        if (j0 > wbase + 15) continue;

        float amadd[4];
#pragma unroll
        for (int nt = 0; nt < 4; nt++)
            amadd[nt] = samadd[j0 + nt * 16 + lrow];

        // QK^T: 16 rows x 64 cols, split 3-MFMA, swizzled B-frag reads
        f32x4 s4[4];
#pragma unroll
        for (int nt = 0; nt < 4; nt++) s4[nt] = (f32x4){0.f, 0.f, 0.f, 0.f};
        __builtin_amdgcn_s_setprio(1);
#pragma unroll
        for (int c = 0; c < 4; c++) {
#pragma unroll
            for (int nt = 0; nt < 4; nt++) {
                int ka = (nt * 16 + lrow) * 128 + (((c * 4 + quad) ^ (lrow & 7)) * 8);
                bf16x8 kb8 = *(const bf16x8*)&skh[ka];
                bf16x8 lb8 = *(const bf16x8*)&skl[ka];
                s4[nt] = mfma16(qhf[c], kb8, s4[nt]);
                s4[nt] = mfma16(qhf[c], lb8, s4[nt]);
                s4[nt] = mfma16(qlf[c], kb8, s4[nt]);
            }
        }
        __builtin_amdgcn_s_setprio(0);

        const bool needmask = (j0 + 63 > wbase);
#pragma unroll
        for (int r = 0; r < 4; r++) {
            const int rglob = wbase + quad * 4 + r;
            float sv[4], pw[4];
            float mx = -INFINITY;
#pragma unroll
            for (int nt = 0; nt < 4; nt++) {
                float xv = s4[nt][r] * scale + amadd[nt];
                if (needmask && (j0 + nt * 16 + lrow) > rglob) xv = -INFINITY;
                sv[nt] = xv;
                mx = fmaxf(mx, xv);
            }
#pragma unroll
            for (int off = 1; off < 16; off <<= 1) mx = fmaxf(mx, __shfl_xor(mx, off));
            float mnew = fmaxf(m_i[r], mx);
            float alpha = __expf(m_i[r] - mnew);
            float ps = 0.f;
#pragma unroll
            for (int nt = 0; nt < 4; nt++) { pw[nt] = __expf(sv[nt] - mnew); ps += pw[nt]; }
#pragma unroll
            for (int off = 1; off < 16; off <<= 1) ps += __shfl_xor(ps, off);
            l_i[r] = l_i[r] * alpha + ps;
            m_i[r] = mnew;
#pragma unroll
            for (int n2 = 0; n2 < 8; n2++) O[n2][r] *= alpha;
#pragma unroll
            for (int nt = 0; nt < 4; nt++)
                sp[wave][(quad * 4 + r) * SPLD + nt * 16 + lrow] = (bf16)pw[nt];
        }
        asm volatile("s_waitcnt lgkmcnt(0)" ::: "memory");   // sp per-wave

        // PV: O += P * V, swizzled V^T frag reads
        __builtin_amdgcn_s_setprio(1);
#pragma unroll
        for (int k2 = 0; k2 < 2; k2++) {
            bf16x8 pf = *(const bf16x8*)&sp[wave][lrow * SPLD + k2 * 32 + quad * 8];
            const int gp = ((quad + k2 * 4) ^ (lrow & 7)) * 8;
#pragma unroll
            for (int n2 = 0; n2 < 8; n2++) {
                bf16x8 vf8 = *(const bf16x8*)&svt[(n2 * 16 + lrow) * 64 + gp];
                O[n2] = mfma16(pf, vf8, O[n2]);
            }
        }
        __builtin_amdgcn_s_setprio(0);
    }

    float inv[4];
#pragma unroll
    for (int r = 0; r < 4; r++) inv[r] = 1.0f / l_i[r];
#pragma unroll
    for (int n2 = 0; n2 < 8; n2++)
#pragma unroll
        for (int r = 0; r < 4; r++) {
            int srow = i0 + wave * 16 + quad * 4 + r;
            outp[((size_t)(b * S_ + srow)) * D_ + h * HD_ + n2 * 16 + lrow] =
                (bf16)(O[n2][r] * inv[r]);
        }
}

// =================== launch ===================
extern "C" void kernel_launch(void* const* d_in, const int* in_sizes, int n_in,
                              void* d_out, int out_size, void* d_ws, size_t ws_size,
                              hipStream_t stream) {
    const float* x  = (const float*)d_in[0];
    const float* qm = (const float*)d_in[1];
    const float* km = (const float*)d_in[2];
    const float* vm = (const float*)d_in[3];
    const float* om = (const float*)d_in[4];
    const float* hm = (const float*)d_in[5];
    const float* am = (const float*)d_in[6];
    const float* sw = (const float*)d_in[7];
    float* out = (float*)d_out;

    const size_t P = (size_t)B_ * H_ * S_ * HD_ * sizeof(bf16);   // 16 MiB
    char* ws = (char*)d_ws;
    bf16* xh = (bf16*)(ws + 0 * P);
    bf16* xl = (bf16*)(ws + 1 * P);
    bf16* qh = (bf16*)(ws + 2 * P);
    bf16* ql = (bf16*)(ws + 3 * P);
    bf16* kh = (bf16*)(ws + 4 * P);
    bf16* kl = (bf16*)(ws + 5 * P);
    bf16* attn_out = xh;
    bf16* vmb = xl;
    bf16* omb = qh;
    bf16* vt  = (bf16*)d_out;
    bf16* qmb = (bf16*)((char*)d_out + 16u * 1024 * 1024);
    bf16* kmb = (bf16*)((char*)d_out + 24u * 1024 * 1024);

    precast_all<<<8192, 256, 0, stream>>>(x, xh, xl, qm, qmb, km, kmb, sw);

    // q/k projection: 256x128 tiles, virtual K=4096 (hi|lo), 512 blocks = 2/CU
    gemm2p<<<dim3(32, 16), 256, 0, stream>>>(
        xh, xl, qmb, kmb, hm, qh, ql, kh, kl, 128);

    // v projection (hi only): 128x128 BK=64 tiles, 512 blocks; writes V^T
    precast_mask<<<2048, 256, 0, stream>>>(vm, vmb, sw);
    gemm64<1><<<dim3(16, 32), 256, 0, stream>>>(
        xh, vmb, hm, vt, nullptr, 32);

    // attention: 512 blocks (r8 mapping), QBLK=128, 8 waves
    attn_kernel<<<512, 512, 0, stream>>>(qh, ql, kh, kl, vt, am, attn_out);

    // output projection: 128x128 BK=64 tiles, 512 blocks, f32 out
    precast_mask<<<2048, 256, 0, stream>>>(om, omb, sw);
    gemm64<2><<<dim3(16, 32), 256, 0, stream>>>(
        attn_out, omb, hm, nullptr, out, 32);
}